// Round 2
// baseline (154.730 us; speedup 1.0000x reference)
//
#include <hip/hip_runtime.h>
#include <math.h>

#define N_PIX 65536
#define EPSF 1e-6f
#define CHUNKS 32
#define PX_PER_CHUNK 2048
#define MACRO_PX 256
#define N_MACROS 8            // 2048 / 256
#define N_JOBS 48             // 2 imgs * 8 batch * 3 channels
#define N_BLOCKS (N_JOBS * CHUNKS)   // 1536
#define N_RBLOCKS (24 * 4)           // 96 reduce blocks
#define LN2_50 34.65735903f // 50 * ln(2): log2 -> scaled-ln

typedef __attribute__((ext_vector_type(2))) float f2;
using short8 = __attribute__((ext_vector_type(8))) short;
using f32x4  = __attribute__((ext_vector_type(4))) float;

__device__ __forceinline__ float rcp_fast(float x) { return __builtin_amdgcn_rcpf(x); }

#if __has_builtin(__builtin_amdgcn_cvt_pk_bf16_f32)
typedef __attribute__((ext_vector_type(2))) __bf16 bf16x2_t;
__device__ __forceinline__ uint32_t pk_bf16(float a, float b) {
    return __builtin_bit_cast(uint32_t, __builtin_amdgcn_cvt_pk_bf16_f32(a, b));
}
#else
// fallback: round-half-up (inputs positive finite), 3 ops
__device__ __forceinline__ uint32_t pk_bf16(float a, float b) {
    const uint32_t ua = __builtin_bit_cast(uint32_t, a) + 0x8000u;
    const uint32_t ub = __builtin_bit_cast(uint32_t, b) + 0x8000u;
    return __builtin_amdgcn_perm(ub, ua, 0x07060302u);
}
#endif

// phase A: pixel -> (u*50, v*50, weight); log2-based (ln2 folded into scale)
__device__ __forceinline__ float4 phaseA(float pr, float pg, float pb, int c) {
    const float r  = pr + EPSF;
    const float g  = pg + EPSF;
    const float bl = pb + EPSF;
    const float wgt = sqrtf(fmaf(r, r, fmaf(g, g, bl * bl)));
    const float lr = __log2f(r), lg = __log2f(g), lb2 = __log2f(bl);
    // channel c: u = l_c - l_a, v = l_c - l_b;  c0:(a,b)=(g,b) c1:(r,b) c2:(r,g)
    const float l0 = (c == 0) ? lr : ((c == 1) ? lg : lb2);
    const float lu = (c == 0) ? lg : lr;
    const float lv = (c == 2) ? lg : lb2;
    return make_float4((l0 - lu) * LN2_50, (l0 - lv) * LN2_50, wgt, 0.0f);
}

// ---------------------------------------------------------------------------
// Kernel 1 (S2-R2): producer-consumer fragment sharing to break the register
// occupancy wall. R1 FAILED on a pure indexing bug: consume() was passed the
// SUB-TILE index as the double-buffer selector, so sub-tiles 2,3 read
// af_lds[2]/af_lds[3] — out of bounds. Fixed: consume(s) derives bufsel=s&1
// (matching produce's s&1 write). Structure unchanged from R1:
// The block's 4 waves SHARE pixels; each wave owns a 64x16 output strip
// (nt = wv, acc[4] = 16 regs vs acc[16]=64 before). Trans work stays optimal
// (each (px,bin) rcp exactly once): wave w evaluates U for center tile mt=w
// (lane center index wv*16+l15 serves both its U rows and its private V
// columns) and the four A-fragments are exchanged via a lane-aligned LDS
// buffer (1 b128 write + 3 b128 reads per K-half, contiguous -> conflict-
// free). 5 barriers per 256-px macro (dbuf uvw + dbuf af). Epilogue: waves
// own disjoint output columns -> direct b128 stores (fixed job-independent
// bijection; reduce is permutation-agnostic). Target: 6 waves/SIMD
// (grid 6 blocks/CU; LDS 25.6KB*6 fits; launch_bounds(256,6) caps regs).
// ---------------------------------------------------------------------------
__global__ __launch_bounds__(256, 6) void hist_kernel(
    const float* __restrict__ x, const float* __restrict__ y,
    float* __restrict__ partial, float* __restrict__ accum)
{
    const int blk = blockIdx.x;            // 0..1535
    const int chunk = blk & (CHUNKS - 1);
    const int job = blk / CHUNKS;          // 0..47
    const int c = job % 3;
    const int ib = job / 3;                // img*8 + b
    const int img = ib >> 3;
    const int b = ib & 7;
    const float* __restrict__ src = (img == 0 ? x : y) + (size_t)b * 3 * N_PIX;

    const int tid = threadIdx.x;
    if (blk == 0 && tid < 25) ((unsigned*)accum)[tid] = 0u;  // accum[24] + ticket

    // uvw: 256 px * float4, +16B pad per 8 px (conflict-free, R5-verified
    // pattern), double-buffered. af: [buf][h*1024 + mt*256 + lane*4] dwords,
    // lane-contiguous b128 (conflict-free), double-buffered per sub-tile.
    __shared__ __align__(16) float uvw_lds[2][1152];   // 2 * 4608 B
    __shared__ __align__(16) int   af_lds[2][2048];    // 2 * 8192 B

    const int lane = tid & 63;
    const int wv = tid >> 6;
    const int quad = lane >> 4;
    const int l15 = lane & 15;

    // this lane's single center (serves U rows mt=wv AND V cols nt=wv)
    const float cc = (-3.0f + (float)(wv * 16 + l15) * (6.0f / 63.0f)) * 50.0f;
    const f2 nc2 = {-cc, -cc};
    const f2 one2 = {1.0f, 1.0f};

    f32x4 acc[4];                          // acc[mt], nt = wv fixed
#pragma unroll
    for (int i = 0; i < 4; ++i) acc[i] = (f32x4){0.f, 0.f, 0.f, 0.f};

    const int px0 = chunk * PX_PER_CHUNK;

    // prefetch macro 0 raw pixels (1 px per thread)
    float pr, pg, pb;
    {
        const int n = px0 + wv * 64 + lane;
        pr = src[n]; pg = src[N_PIX + n]; pb = src[2 * N_PIX + n];
    }

    short8 bfh0, bfh1;                     // private B fragments (2 K-halves)

    // produce(s): U+V eval for sub-tile s (64 px), writes af buf s&1. U words
    // (center tile mt=wv, w folded in) -> af_lds[s&1]; V words -> regs (bfh).
    auto produce = [&](const float* __restrict__ ub, int s) {
        const int bufsel = s & 1;
#pragma unroll
        for (int h = 0; h < 2; ++h) {
            const int pxb = s * 64 + h * 32 + quad * 8;
            const float4* __restrict__ pbase =
                (const float4*)(ub + pxb * 4 + (pxb >> 3) * 4);
            int aw[4], bw[4];
#pragma unroll
            for (int jp = 0; jp < 4; ++jp) {
                const float4 pe = pbase[2 * jp];
                const float4 po = pbase[2 * jp + 1];
                const f2 ru2 = {pe.x, po.x};
                const f2 rv2 = {pe.y, po.y};
                const f2 rw2 = {pe.z, po.z};
                const f2 tu = ru2 + nc2;
                const f2 tv = rv2 + nc2;
                const f2 qu = __builtin_elementwise_fma(tu, tu, one2);
                const f2 qv = __builtin_elementwise_fma(tv, tv, one2);
                const f2 au = (f2){rcp_fast(qu.x), rcp_fast(qu.y)} * rw2;
                aw[jp] = (int)pk_bf16(au.x, au.y);
                bw[jp] = (int)pk_bf16(rcp_fast(qv.x), rcp_fast(qv.y));
            }
            *(int4*)(&af_lds[bufsel][h * 1024 + wv * 256 + lane * 4]) =
                make_int4(aw[0], aw[1], aw[2], aw[3]);
            const short8 bwv =
                __builtin_bit_cast(short8, make_int4(bw[0], bw[1], bw[2], bw[3]));
            if (h == 0) bfh0 = bwv; else bfh1 = bwv;
        }
    };
    // consume(s): read all 4 waves' A-fragments for sub-tile s from buf s&1
    // (lane-aligned, same register content as self-computed), 8 MFMAs into
    // the wave's column strip. bfh holds sub-tile s's V by program order.
    auto consume = [&](int s) {
        const int bufsel = s & 1;
#pragma unroll
        for (int h = 0; h < 2; ++h) {
            short8 af[4];
#pragma unroll
            for (int mt = 0; mt < 4; ++mt)
                af[mt] = __builtin_bit_cast(short8,
                    *(const int4*)(&af_lds[bufsel][h * 1024 + mt * 256 + lane * 4]));
            const short8 bh = (h == 0) ? bfh0 : bfh1;
#pragma unroll
            for (int mt = 0; mt < 4; ++mt)
                acc[mt] = __builtin_amdgcn_mfma_f32_16x16x32_bf16(
                    af[mt], bh, acc[mt], 0, 0, 0);
        }
    };

#pragma unroll 1
    for (int m = 0; m < N_MACROS; ++m) {
        // ---- phase A: 256 px block-wide (1 px/thread) -> uvw[m&1] ----
        {
            const float4 uvw = phaseA(pr, pg, pb, c);
            const int pxw = wv * 64 + lane;
            *(float4*)(&uvw_lds[m & 1][pxw * 4 + (pxw >> 3) * 4]) = uvw;
        }
        __syncthreads();                   // uvw[m&1] ready

        // prefetch next macro right after the barrier: the vmcnt(0) drain at
        // the NEXT barrier is covered by produce(0)'s ~400 cycles of work
        float nr = 0.f, ng = 0.f, nb = 0.f;
        if (m + 1 < N_MACROS) {
            const int n2 = px0 + (m + 1) * 256 + wv * 64 + lane;
            nr = src[n2]; ng = src[N_PIX + n2]; nb = src[2 * N_PIX + n2];
        }

        const float* __restrict__ ub = &uvw_lds[m & 1][0];
        produce(ub, 0);
        __syncthreads();                   // af buf0 (s=0) ready
        consume(0); produce(ub, 1);
        __syncthreads();                   // af buf1 (s=1) ready, buf0 readers done
        consume(1); produce(ub, 2);
        __syncthreads();                   // af buf0 (s=2) ready, buf1 readers done
        consume(2); produce(ub, 3);
        __syncthreads();                   // af buf1 (s=3) ready, buf0 readers done
        consume(3);

        pr = nr; pg = ng; pb = nb;
    }

    // ---- Epilogue: waves own disjoint column strips -> direct b128 stores,
    // fixed job-independent element permutation (reduce is elementwise) ----
    float* __restrict__ outp = partial + (size_t)blk * 4096 + wv * 1024;
#pragma unroll
    for (int mt = 0; mt < 4; ++mt)
        *(f32x4*)(outp + mt * 256 + lane * 4) = acc[mt];
}

// ---------------------------------------------------------------------------
// Kernel 2: Bhattacharyya-factored reduction + fused finalize. (unchanged)
//   sum (sqrt(y/TY)-sqrt(x/TX))^2 = 2(1 - rho), rho = sum sqrt(sx*sy)/sqrt(TX*TY)
// 96 blocks x 256 (24 x-jobs x 4 slices): each thread owns one element-QUAD;
// accumulates qx, qy over the 32 chunk-partials with contiguous f32x4 loads,
// then sx=Σqx, sy=Σqy, cr=Σ sqrt(qx*qy). Block-reduce 3 scalars, 3 device
// atomicAdds; tid0 RELEASE-ticket; the 96th block ACQUIRE-loads accum and
// writes out[0].
// ---------------------------------------------------------------------------
__global__ __launch_bounds__(256) void reduce_cross_kernel(
    const float* __restrict__ partial, float* __restrict__ accum,
    float* __restrict__ out)
{
    unsigned* __restrict__ ticket = (unsigned*)(accum + 24);
    const int jx = blockIdx.x >> 2;                        // 0..23 (img0 job)
    const int bb = jx / 3;                                 // batch 0..7
    const int e4 = (((blockIdx.x & 3) << 8) | threadIdx.x) * 4;  // 0..4092
    const float* px = partial + (size_t)jx * CHUNKS * 4096 + e4;
    const float* py = partial + (size_t)(24 + jx) * CHUNKS * 4096 + e4;

    f32x4 qx = {0.f, 0.f, 0.f, 0.f}, qy = {0.f, 0.f, 0.f, 0.f};
#pragma unroll 8
    for (int k = 0; k < CHUNKS; ++k) {
        qx += *(const f32x4*)(px + (size_t)k * 4096);
        qy += *(const f32x4*)(py + (size_t)k * 4096);
    }
    float sx = (qx.x + qx.y) + (qx.z + qx.w);
    float sy = (qy.x + qy.y) + (qy.z + qy.w);
    float cr = (sqrtf(qx.x * qy.x) + sqrtf(qx.y * qy.y)) +
               (sqrtf(qx.z * qy.z) + sqrtf(qx.w * qy.w));

#pragma unroll
    for (int o = 32; o > 0; o >>= 1) {
        sx += __shfl_down(sx, o, 64);
        sy += __shfl_down(sy, o, 64);
        cr += __shfl_down(cr, o, 64);
    }
    __shared__ float red[12];
    const int wv = threadIdx.x >> 6;
    if ((threadIdx.x & 63) == 0) {
        red[wv] = sx; red[4 + wv] = sy; red[8 + wv] = cr;
    }
    __syncthreads();
    if (threadIdx.x == 0) {
        atomicAdd(&accum[bb],      red[0] + red[1] + red[2] + red[3]);
        atomicAdd(&accum[8 + bb],  red[4] + red[5] + red[6] + red[7]);
        atomicAdd(&accum[16 + bb], red[8] + red[9] + red[10] + red[11]);
        const unsigned old = __hip_atomic_fetch_add(ticket, 1u,
                                 __ATOMIC_ACQ_REL, __HIP_MEMORY_SCOPE_AGENT);
        if (old == N_RBLOCKS - 1) {        // last arriver: all atomicAdds visible
            float s = 0.0f;
#pragma unroll
            for (int b = 0; b < 8; ++b) {
                const float tx = __hip_atomic_load(&accum[b],      __ATOMIC_ACQUIRE, __HIP_MEMORY_SCOPE_AGENT);
                const float ty = __hip_atomic_load(&accum[8 + b],  __ATOMIC_ACQUIRE, __HIP_MEMORY_SCOPE_AGENT);
                const float cc = __hip_atomic_load(&accum[16 + b], __ATOMIC_ACQUIRE, __HIP_MEMORY_SCOPE_AGENT);
                const float rho = cc * __builtin_amdgcn_rsqf(tx * ty);
                s += sqrtf(fmaxf(1.0f - rho, 0.0f));
            }
            out[0] = s * 0.125f;
        }
    }
}

extern "C" void kernel_launch(void* const* d_in, const int* in_sizes, int n_in,
                              void* d_out, int out_size, void* d_ws, size_t ws_size,
                              hipStream_t stream)
{
    const float* x = (const float*)d_in[0];
    const float* y = (const float*)d_in[1];
    float* ws = (float*)d_ws;
    float* partial = ws;                                  // 1536*4096 floats (25.2 MB)
    float* accum = ws + (size_t)N_BLOCKS * 4096;          // 24 floats + ticket
    float* outf = (float*)d_out;

    hipLaunchKernelGGL(hist_kernel, dim3(N_BLOCKS), dim3(256), 0, stream,
                       x, y, partial, accum);
    hipLaunchKernelGGL(reduce_cross_kernel, dim3(N_RBLOCKS), dim3(256), 0, stream,
                       partial, accum, outf);
}